// Round 3
// baseline (118.357 us; speedup 1.0000x reference)
//
#include <hip/hip_runtime.h>

// MultiThresholdLIFSpike: x [T=16, B=32, C=128, H=32, W=32] f32, raw thresholds [4] f32.
// Per spatial element, scan over T:
//   u = 0.25*mem*(1-spike) + x_t
//   s = sum_k sigmoid(10*(u - thr_k)),  thr_k = sigmoid(raw_k)
//   mem = u; spike = s; out[t] = s
//
// Shared-exp trick: sigmoid(B*(u-thr_k)) = 1/(1 + e^{-B*u} * e^{B*thr_k})
//   -> ONE v_exp_f32 per element-step + 4 precomputed c_k = 2^(S*thr_k),
//      S = B*log2(e). Four v_rcp_f32 remain. 5 trans ops vs 8.
// Saturation-safe: u << 0 -> E=inf -> each term rcp(inf)=0 -> s=0 (correct);
//                  u >> 0 -> E=0   -> each term rcp(1)=1  -> s=4 (correct).
// 16 loads prefetched up front; nontemporal (streaming, zero reuse).

#define T_STEPS 16
#define NTHR 4

typedef float v4f __attribute__((ext_vector_type(4)));

__global__ __launch_bounds__(256) void lif_spike_kernel(
    const float* __restrict__ x,
    const float* __restrict__ raw_thr,
    float* __restrict__ out,
    int n4 /* float4 groups per timestep */) {

    int i = blockIdx.x * blockDim.x + threadIdx.x;
    if (i >= n4) return;

    constexpr float LOG2E = 1.44269504088896340736f;
    constexpr float BETA  = 10.0f;
    constexpr float TAU   = 0.25f;
    constexpr float S     = BETA * LOG2E;   // 14.426950...

    // c_k = 2^(S * sigmoid(raw_k)); 4 broadcast loads, cached
    float ck[NTHR];
#pragma unroll
    for (int k = 0; k < NTHR; ++k) {
        float r   = raw_thr[k];
        float thr = __builtin_amdgcn_rcpf(1.0f + __builtin_amdgcn_exp2f(-LOG2E * r));
        ck[k] = __builtin_amdgcn_exp2f(S * thr);
    }

    const v4f* xv = reinterpret_cast<const v4f*>(x) + i;
    v4f*       ov = reinterpret_cast<v4f*>(out) + i;

    // Prefetch all 16 timesteps (independent of the recurrence) so the
    // 16 global_load_dwordx4 issue back-to-back at full HBM rate.
    v4f xt[T_STEPS];
#pragma unroll
    for (int t = 0; t < T_STEPS; ++t)
        xt[t] = __builtin_nontemporal_load(xv + (size_t)t * (size_t)n4);

    float mem[4] = {0.f, 0.f, 0.f, 0.f};
    float spk[4] = {0.f, 0.f, 0.f, 0.f};

#pragma unroll
    for (int t = 0; t < T_STEPS; ++t) {
        float s[4];
#pragma unroll
        for (int j = 0; j < 4; ++j) {
            float tm = TAU * mem[j];
            float u  = __builtin_fmaf(-tm, spk[j], tm) + xt[t][j];  // tm*(1-spk)+x
            float E  = __builtin_amdgcn_exp2f(-S * u);              // e^{-B*u}
            float acc = 0.f;
#pragma unroll
            for (int k = 0; k < NTHR; ++k)
                acc += __builtin_amdgcn_rcpf(__builtin_fmaf(E, ck[k], 1.0f));
            s[j]   = acc;
            mem[j] = u;
            spk[j] = acc;
        }
        v4f o = {s[0], s[1], s[2], s[3]};
        __builtin_nontemporal_store(o, ov + (size_t)t * (size_t)n4);
    }
}

extern "C" void kernel_launch(void* const* d_in, const int* in_sizes, int n_in,
                              void* d_out, int out_size, void* d_ws, size_t ws_size,
                              hipStream_t stream) {
    const float* x       = (const float*)d_in[0];
    const float* raw_thr = (const float*)d_in[1];
    float*       out     = (float*)d_out;

    int n_spatial = in_sizes[0] / T_STEPS;   // 4,194,304
    int n4        = n_spatial / 4;           // 1,048,576

    const int block = 256;
    const int grid  = (n4 + block - 1) / block;  // 4096 blocks

    lif_spike_kernel<<<grid, block, 0, stream>>>(x, raw_thr, out, n4);
}

// Round 4
// 112.296 us; speedup vs baseline: 1.0540x; 1.0540x over previous
//
#include <hip/hip_runtime.h>

// MultiThresholdLIFSpike: x [T=16, B=32, C=128, H=32, W=32] f32, raw thresholds [4] f32.
// Per spatial element, scan over T:
//   u = 0.25*mem*(1-spike) + x_t
//   s = sum_k sigmoid(10*(u - thr_k)),  thr_k = sigmoid(raw_k)
//   mem = u; spike = s; out[t] = s
//
// R4: R1's interleaved low-VGPR structure (8 waves/SIMD) + shared-exp sigmoid:
//   sigmoid(B*(u-thr_k)) = 1/(1 + e^{-B*u} * e^{B*thr_k})
//   -> ONE v_exp_f32 per element-step + 4 precomputed c_k = 2^(S*thr_k),
//      S = B*log2(e). 5 trans ops/elem-step vs 8.
// Saturation-safe: u << 0 -> E=inf -> each term rcp(inf)=0 -> s=0 (correct);
//                  u >> 0 -> E=0   -> each term rcp(1)=1  -> s=4 (correct).
// No prefetch-all (R3: 64-VGPR payload buffer halved occupancy, -7%).
// No nontemporal (R3 bundle regressed; normal path sustains 7 TB/s on fills).

#define T_STEPS 16
#define NTHR 4

typedef float v4f __attribute__((ext_vector_type(4)));

__global__ __launch_bounds__(256) void lif_spike_kernel(
    const float* __restrict__ x,
    const float* __restrict__ raw_thr,
    float* __restrict__ out,
    int n4 /* float4 groups per timestep */) {

    int i = blockIdx.x * blockDim.x + threadIdx.x;
    if (i >= n4) return;

    constexpr float LOG2E = 1.44269504088896340736f;
    constexpr float BETA  = 10.0f;
    constexpr float TAU   = 0.25f;
    constexpr float S     = BETA * LOG2E;   // 14.426950...

    // c_k = 2^(S * sigmoid(raw_k)); 4 broadcast loads, cached
    float ck[NTHR];
#pragma unroll
    for (int k = 0; k < NTHR; ++k) {
        float r   = raw_thr[k];
        float thr = __builtin_amdgcn_rcpf(1.0f + __builtin_amdgcn_exp2f(-LOG2E * r));
        ck[k] = __builtin_amdgcn_exp2f(S * thr);
    }

    const v4f* xv = reinterpret_cast<const v4f*>(x) + i;
    v4f*       ov = reinterpret_cast<v4f*>(out) + i;

    float mem[4] = {0.f, 0.f, 0.f, 0.f};
    float spk[4] = {0.f, 0.f, 0.f, 0.f};

#pragma unroll
    for (int t = 0; t < T_STEPS; ++t) {
        v4f xt = xv[(size_t)t * (size_t)n4];

        float s[4];
#pragma unroll
        for (int j = 0; j < 4; ++j) {
            float tm = TAU * mem[j];
            float u  = __builtin_fmaf(-tm, spk[j], tm) + xt[j];  // tm*(1-spk)+x
            float E  = __builtin_amdgcn_exp2f(-S * u);           // e^{-B*u}
            float acc = 0.f;
#pragma unroll
            for (int k = 0; k < NTHR; ++k)
                acc += __builtin_amdgcn_rcpf(__builtin_fmaf(E, ck[k], 1.0f));
            s[j]   = acc;
            mem[j] = u;
            spk[j] = acc;
        }
        v4f o = {s[0], s[1], s[2], s[3]};
        ov[(size_t)t * (size_t)n4] = o;
    }
}

extern "C" void kernel_launch(void* const* d_in, const int* in_sizes, int n_in,
                              void* d_out, int out_size, void* d_ws, size_t ws_size,
                              hipStream_t stream) {
    const float* x       = (const float*)d_in[0];
    const float* raw_thr = (const float*)d_in[1];
    float*       out     = (float*)d_out;

    int n_spatial = in_sizes[0] / T_STEPS;   // 4,194,304
    int n4        = n_spatial / 4;           // 1,048,576

    const int block = 256;
    const int grid  = (n4 + block - 1) / block;  // 4096 blocks

    lif_spike_kernel<<<grid, block, 0, stream>>>(x, raw_thr, out, n4);
}

// Round 5
// 110.912 us; speedup vs baseline: 1.0671x; 1.0125x over previous
//
#include <hip/hip_runtime.h>

// MultiThresholdLIFSpike: x [T=16, B=32, C=128, H=32, W=32] f32, raw thresholds [4] f32.
// Per spatial element, scan over T:
//   u = 0.25*mem*(1-spike) + x_t
//   s = sum_k sigmoid(10*(u - thr_k)),  thr_k = sigmoid(raw_k)
//   mem = u; spike = s; out[t] = s
//
// R5: occupancy + MLP push.
//  - __launch_bounds__(256, 8): cap VGPR at 64 -> 8 waves/SIMD (occupancy
//    halves above 64 VGPR; suspect R1/R4 compiler-hoisting pushed past it).
//  - ILP-2: each thread runs TWO independent recurrence chains (spatial
//    groups i and i+n4/2) -> 2 independent load/store streams per thread.
//    Grid 2048 blocks = 524288 threads = 8192 waves = exactly 32/CU resident.
//  - shared-exp sigmoid kept (neutral on time, fewer ops, same absmax):
//    sigmoid(B*(u-thr_k)) = 1/(1 + e^{-B*u} * 2^(S*thr_k)), S = B*log2(e).

#define T_STEPS 16
#define NTHR 4

typedef float v4f __attribute__((ext_vector_type(4)));

__global__ __launch_bounds__(256, 8) void lif_spike_kernel(
    const float* __restrict__ x,
    const float* __restrict__ raw_thr,
    float* __restrict__ out,
    int n4 /* float4 groups per timestep */) {

    int half = n4 >> 1;
    int i = blockIdx.x * blockDim.x + threadIdx.x;
    if (i >= half) return;

    constexpr float LOG2E = 1.44269504088896340736f;
    constexpr float BETA  = 10.0f;
    constexpr float TAU   = 0.25f;
    constexpr float S     = BETA * LOG2E;

    float ck[NTHR];
#pragma unroll
    for (int k = 0; k < NTHR; ++k) {
        float r   = raw_thr[k];
        float thr = __builtin_amdgcn_rcpf(1.0f + __builtin_amdgcn_exp2f(-LOG2E * r));
        ck[k] = __builtin_amdgcn_exp2f(S * thr);
    }

    const v4f* xvA = reinterpret_cast<const v4f*>(x) + i;
    const v4f* xvB = xvA + half;
    v4f*       ovA = reinterpret_cast<v4f*>(out) + i;
    v4f*       ovB = ovA + half;

    float memA[4] = {0.f, 0.f, 0.f, 0.f};
    float spkA[4] = {0.f, 0.f, 0.f, 0.f};
    float memB[4] = {0.f, 0.f, 0.f, 0.f};
    float spkB[4] = {0.f, 0.f, 0.f, 0.f};

#pragma unroll
    for (int t = 0; t < T_STEPS; ++t) {
        size_t off = (size_t)t * (size_t)n4;
        v4f xa = xvA[off];
        v4f xb = xvB[off];

        float sa[4], sb[4];
#pragma unroll
        for (int j = 0; j < 4; ++j) {
            // chain A
            float tmA = TAU * memA[j];
            float uA  = __builtin_fmaf(-tmA, spkA[j], tmA) + xa[j];
            float EA  = __builtin_amdgcn_exp2f(-S * uA);
            float accA = 0.f;
#pragma unroll
            for (int k = 0; k < NTHR; ++k)
                accA += __builtin_amdgcn_rcpf(__builtin_fmaf(EA, ck[k], 1.0f));
            memA[j] = uA; spkA[j] = accA; sa[j] = accA;
            // chain B (independent)
            float tmB = TAU * memB[j];
            float uB  = __builtin_fmaf(-tmB, spkB[j], tmB) + xb[j];
            float EB  = __builtin_amdgcn_exp2f(-S * uB);
            float accB = 0.f;
#pragma unroll
            for (int k = 0; k < NTHR; ++k)
                accB += __builtin_amdgcn_rcpf(__builtin_fmaf(EB, ck[k], 1.0f));
            memB[j] = uB; spkB[j] = accB; sb[j] = accB;
        }
        v4f oa = {sa[0], sa[1], sa[2], sa[3]};
        v4f ob = {sb[0], sb[1], sb[2], sb[3]};
        ovA[off] = oa;
        ovB[off] = ob;
    }
}

extern "C" void kernel_launch(void* const* d_in, const int* in_sizes, int n_in,
                              void* d_out, int out_size, void* d_ws, size_t ws_size,
                              hipStream_t stream) {
    const float* x       = (const float*)d_in[0];
    const float* raw_thr = (const float*)d_in[1];
    float*       out     = (float*)d_out;

    int n_spatial = in_sizes[0] / T_STEPS;   // 4,194,304
    int n4        = n_spatial / 4;           // 1,048,576
    int half      = n4 / 2;                  // 524,288 threads

    const int block = 256;
    const int grid  = (half + block - 1) / block;  // 2048 blocks

    lif_spike_kernel<<<grid, block, 0, stream>>>(x, raw_thr, out, n4);
}